// Round 6
// baseline (279.146 us; speedup 1.0000x reference)
//
#include <hip/hip_runtime.h>
#include <limits.h>

#define S_U 256
#define N_IMP 128
#define OUT_STRIDE (4 + N_IMP)
#define TRUNC 0.015625f   // 2/512*4
#define WPB 4             // waves per 256-thread block
#define INV127 (1.0f / 127.0f)
#define MAX_BLOCKS 2048   // 2048*4 = 8192 waves = every wave slot on the chip

// ---------------- DPP cross-lane helpers (no LDS/ds_bpermute) ----------------
template<int CTRL, int RM, int BM>
__device__ __forceinline__ int dpp_i(int old_, int x) {
    return __builtin_amdgcn_update_dpp(old_, x, CTRL, RM, BM, false);
}
template<int CTRL, int RM, int BM>
__device__ __forceinline__ float dpp_f(float old_, float x) {
    return __int_as_float(__builtin_amdgcn_update_dpp(
        __float_as_int(old_), __float_as_int(x), CTRL, RM, BM, false));
}
__device__ __forceinline__ float readlane_f(float x, int l) {
    return __int_as_float(__builtin_amdgcn_readlane(__float_as_int(x), l));
}

// Full-wave inclusive scans (lane63 ends with the total).
__device__ __forceinline__ float wscan_add(float x) {
    x += dpp_f<0x111,0xf,0xf>(0.0f, x);
    x += dpp_f<0x112,0xf,0xf>(0.0f, x);
    x += dpp_f<0x114,0xf,0xf>(0.0f, x);
    x += dpp_f<0x118,0xf,0xf>(0.0f, x);
    x += dpp_f<0x142,0xa,0xf>(0.0f, x);
    x += dpp_f<0x143,0xc,0xf>(0.0f, x);
    return x;
}
__device__ __forceinline__ float wscan_mul(float x) {
    x *= dpp_f<0x111,0xf,0xf>(1.0f, x);
    x *= dpp_f<0x112,0xf,0xf>(1.0f, x);
    x *= dpp_f<0x114,0xf,0xf>(1.0f, x);
    x *= dpp_f<0x118,0xf,0xf>(1.0f, x);
    x *= dpp_f<0x142,0xa,0xf>(1.0f, x);
    x *= dpp_f<0x143,0xc,0xf>(1.0f, x);
    return x;
}
__device__ __forceinline__ int wscan_max(int x) {   // values >= 0
    x = max(x, dpp_i<0x111,0xf,0xf>(0, x));
    x = max(x, dpp_i<0x112,0xf,0xf>(0, x));
    x = max(x, dpp_i<0x114,0xf,0xf>(0, x));
    x = max(x, dpp_i<0x118,0xf,0xf>(0, x));
    x = max(x, dpp_i<0x142,0xa,0xf>(0, x));
    x = max(x, dpp_i<0x143,0xc,0xf>(0, x));
    return x;
}
__device__ __forceinline__ int wred_min(int x) {    // result valid in lane 63
    x = min(x, dpp_i<0x111,0xf,0xf>(INT_MAX, x));
    x = min(x, dpp_i<0x112,0xf,0xf>(INT_MAX, x));
    x = min(x, dpp_i<0x114,0xf,0xf>(INT_MAX, x));
    x = min(x, dpp_i<0x118,0xf,0xf>(INT_MAX, x));
    x = min(x, dpp_i<0x142,0xa,0xf>(INT_MAX, x));
    x = min(x, dpp_i<0x143,0xc,0xf>(INT_MAX, x));
    return x;
}

// Exact jmin = min{ j in [0,128] : (float)j * INV127 >= c }  (128 == "no sample")
__device__ __forceinline__ int jm_of(float c) {
    int jm = (int)ceilf(c * 127.0f);
    jm = min(max(jm, 0), 128);
    if (jm > 0 && (float)(jm - 1) * INV127 >= c) jm--;
    else if (jm < 128 && (float)jm * INV127 < c) jm++;
    return jm;
}

__global__ __launch_bounds__(256) void tsdf_render_kernel(
    const float* __restrict__ occ,
    const float* __restrict__ zvals,
    const float* __restrict__ sdf,
    const float* __restrict__ rgbs,
    float* __restrict__ out,
    int n_rays)
{
    const int lane = threadIdx.x & 63;
    const int wv   = threadIdx.x >> 6;
    const int rstride = gridDim.x * WPB;
    int ray = blockIdx.x * WPB + wv;

    __shared__ __align__(16) float s_cdf [WPB][S_U];
    __shared__ __align__(16) float s_zmid[WPB][S_U];
    __shared__ __align__(16) int   s_bs  [WPB][N_IMP];

    if (ray >= n_rays) return;                    // wave-uniform

    // prologue: all 6 streams of the first ray
    float4 o4  = ((const float4*)(occ   + (size_t)ray * S_U))[lane];
    float4 z4  = ((const float4*)(zvals + (size_t)ray * S_U))[lane];
    float2 sd2 = ((const float2*)(sdf   + (size_t)ray * N_IMP))[lane];
    {
        const float2* rg0 = (const float2*)(rgbs + (size_t)ray * (N_IMP * 3)) + lane * 3;
        // loaded below into p0..p2 via first-iteration prefetch copy pattern
    }
    const float2* rg_ = (const float2*)(rgbs + (size_t)ray * (N_IMP * 3)) + lane * 3;
    float2 p0 = rg_[0], p1 = rg_[1], p2 = rg_[2];

    for (;;) {
        // ---- prefetch ALL six streams of the next ray (covered by compute) ----
        const int nray = ray + rstride;
        const bool more = nray < n_rays;          // wave-uniform
        const int pray = more ? nray : ray;       // clamp: re-read (L1-hot), discarded
        float4 o4n  = ((const float4*)(occ   + (size_t)pray * S_U))[lane];
        float4 z4n  = ((const float4*)(zvals + (size_t)pray * S_U))[lane];
        float2 sd2n = ((const float2*)(sdf   + (size_t)pray * N_IMP))[lane];
        const float2* rgn = (const float2*)(rgbs + (size_t)pray * (N_IMP * 3)) + lane * 3;
        float2 p0n = rgn[0], p1n = rgn[1], p2n = rgn[2];

        // ---------------- coarse occupancy -> weights -----------------------
        float a0 = 1.0f / (1.0f + __expf(-10.0f * o4.x));
        float a1 = 1.0f / (1.0f + __expf(-10.0f * o4.y));
        float a2 = 1.0f / (1.0f + __expf(-10.0f * o4.z));
        float a3 = 1.0f / (1.0f + __expf(-10.0f * o4.w));
        float t0 = 1.0f - a0 + 1e-10f;
        float t1 = 1.0f - a1 + 1e-10f;
        float t2 = 1.0f - a2 + 1e-10f;
        float t3 = 1.0f - a3 + 1e-10f;

        float pp0 = t0, pp1 = pp0 * t1, pp2 = pp1 * t2, pp3 = pp2 * t3;
        float P = wscan_mul(pp3);
        float pbase = dpp_f<0x138,0xf,0xf>(1.0f, P);   // wave_shr1, lane0 = 1

        float w0 = a0 * pbase;
        float w1 = a1 * pbase * pp0;
        float w2 = a2 * pbase * pp1;
        float w3 = a3 * pbase * pp2;

        // ---------------- CDF over w_u[1..254] + 1e-5 -----------------------
        float v0 = (lane > 0)  ? w0 + 1e-5f : 0.0f;
        float v1 = w1 + 1e-5f;
        float v2 = w2 + 1e-5f;
        float v3 = (lane < 63) ? w3 + 1e-5f : 0.0f;
        float s0 = v0, s1 = s0 + v1, s2 = s1 + v2, s3 = s2 + v3;
        float S  = wscan_add(s3);
        float sbase = dpp_f<0x138,0xf,0xf>(0.0f, S);
        float total = readlane_f(S, 63);
        float invt = 1.0f / total;                     // exact (feeds bin decisions)

        float4 cdf4;
        cdf4.x = (sbase + s0) * invt;
        cdf4.y = (sbase + s1) * invt;
        cdf4.z = (sbase + s2) * invt;
        cdf4.w = (sbase + s3) * invt;

        float znext = dpp_f<0x130,0xf,0xf>(z4.x, z4.x); // wave_shl1
        float4 zm4;
        zm4.x = 0.5f * (z4.x + z4.y);
        zm4.y = 0.5f * (z4.y + z4.z);
        zm4.z = 0.5f * (z4.z + z4.w);
        zm4.w = 0.5f * (z4.w + znext);

        __builtin_amdgcn_wave_barrier();   // fence prev iteration's LDS gathers
        *((float4*)&s_cdf [wv][lane * 4]) = cdf4;
        *((float4*)&s_zmid[wv][lane * 4]) = zm4;
        *((int2*)&s_bs[wv][lane * 2]) = make_int2(0, 0);
        __builtin_amdgcn_wave_barrier();   // writes before scatter

        // ---------------- analytic CDF inversion ----------------------------
        int jm0 = jm_of(cdf4.x);
        int jm1 = jm_of(cdf4.y);
        int jm2 = jm_of(cdf4.z);
        int jm3 = jm_of(cdf4.w);
        if (lane == 63) jm3 = 128;
        int jmn = dpp_i<0x130,0xf,0xf>(128, jm0);

        int ib = lane * 4;
        if (jm0 < jm1) s_bs[wv][jm0] = ib;
        if (jm1 < jm2) s_bs[wv][jm1] = ib + 1;
        if (jm2 < jm3) s_bs[wv][jm2] = ib + 2;
        if (jm3 < jmn) s_bs[wv][jm3] = ib + 3;
        __builtin_amdgcn_wave_barrier();   // scatter before fill-read

        int2 bse = *((const int2*)&s_bs[wv][lane * 2]);
        int H  = wscan_max(max(bse.x, bse.y));
        int Hp = dpp_i<0x138,0xf,0xf>(0, H);
        int b0 = max(Hp, bse.x);
        int b1 = H;

        // ---------------- gather + interpolate ------------------------------
        const float* cdfp = s_cdf[wv];
        const float* zmp  = s_zmid[wv];
        float u0 = (float)(2 * lane)     * INV127;
        float u1 = (float)(2 * lane + 1) * INV127;

        float cb0 = cdfp[b0], ca0 = cdfp[b0 + 1];
        float zb0 = zmp[b0],  za0 = zmp[b0 + 1];
        float cb1 = cdfp[b1], ca1 = cdfp[b1 + 1];
        float zb1 = zmp[b1],  za1 = zmp[b1 + 1];

        float d0 = ca0 - cb0; d0 = (d0 < 1e-5f) ? 1.0f : d0;
        float d1 = ca1 - cb1; d1 = (d1 < 1e-5f) ? 1.0f : d1;
        float tt0 = (u0 - cb0) * __builtin_amdgcn_rcpf(d0);
        float tt1 = (u1 - cb1) * __builtin_amdgcn_rcpf(d1);
        float zs0 = zb0 + tt0 * (za0 - zb0);
        float zs1 = zb1 + tt1 * (za1 - zb1);

        // ---------------- first zero-crossing of sdf ------------------------
        float sn = dpp_f<0x130,0xf,0xf>(sd2.x, sd2.x);
        int c = INT_MAX;
        if (sd2.x * sd2.y < 0.0f)                  c = 2 * lane;
        else if (lane < 63 && sd2.y * sn < 0.0f)   c = 2 * lane + 1;
        c = wred_min(c);
        int cis = __builtin_amdgcn_readlane(c, 63);
        cis = (cis == INT_MAX) ? 0 : cis;
        float zca = readlane_f(zs0, cis >> 1);
        float zcb = readlane_f(zs1, cis >> 1);
        float z_min = (cis & 1) ? zcb : zca;

        // ---------------- TSDF alpha + truncation mask ----------------------
        float x0 = sd2.x * (1.0f / TRUNC);
        float x1 = sd2.y * (1.0f / TRUNC);
        float al0 = __builtin_amdgcn_rcpf(2.0f + __expf(x0) + __expf(-x0));
        float al1 = __builtin_amdgcn_rcpf(2.0f + __expf(x1) + __expf(-x1));
        float zlim = z_min + TRUNC;
        if (!(zs0 < zlim)) al0 = 0.0f;
        if (!(zs1 < zlim)) al1 = 0.0f;

        float At = wscan_add(al0 + al1);
        float asum = readlane_f(At, 63);
        float inv_s = __builtin_amdgcn_rcpf(asum + 1e-8f);
        float g0 = al0 * inv_s;
        float g1 = al1 * inv_s;

        // ---------------- composite (lane63 holds the totals) ---------------
        float rr = wscan_add(g0 * p0.x + g1 * p1.y);
        float gg = wscan_add(g0 * p0.y + g1 * p2.x);
        float bb = wscan_add(g0 * p1.x + g1 * p2.y);
        float dd = wscan_add(g0 * zs0  + g1 * zs1);

        float* ob = out + (size_t)ray * OUT_STRIDE;
        ((float2*)(ob + 4))[lane] = make_float2(g0, g1);
        if (lane == 63) {
            ob[0] = fminf(fmaxf(rr, 0.0f), 1.0f);
            ob[1] = fminf(fmaxf(gg, 0.0f), 1.0f);
            ob[2] = fminf(fmaxf(bb, 0.0f), 1.0f);
            ob[3] = dd;
        }

        if (!more) break;
        ray = nray;
        o4 = o4n; z4 = z4n; sd2 = sd2n; p0 = p0n; p1 = p1n; p2 = p2n;
    }
}

extern "C" void kernel_launch(void* const* d_in, const int* in_sizes, int n_in,
                              void* d_out, int out_size, void* d_ws, size_t ws_size,
                              hipStream_t stream) {
    const float* occ  = (const float*)d_in[0];
    const float* z    = (const float*)d_in[1];
    const float* sdf  = (const float*)d_in[2];
    const float* rgbs = (const float*)d_in[3];
    float* out = (float*)d_out;
    const int n_rays = in_sizes[0] / S_U;
    int nblk = (n_rays + WPB - 1) / WPB;
    if (nblk > MAX_BLOCKS) nblk = MAX_BLOCKS;
    hipLaunchKernelGGL(tsdf_render_kernel, dim3(nblk), dim3(256), 0, stream,
                       occ, z, sdf, rgbs, out, n_rays);
}